// Round 2
// 719.205 us; speedup vs baseline: 1.0673x; 1.0673x over previous
//
#include <hip/hip_runtime.h>

// ArcMarginProduct: out[b,c] = S * (c==label[b] ? phi : cos)
//   cos = <input_b/||input_b||, weight_c/||weight_c||>
//   phi = cos*cos(m) - sine*sin(m), fallback cos - S*sin(m)*m if cos <= cos(pi-m)
// B=1024, D=512, C=100000. fp32 in/out; bf16 MFMA inside.
//
// R1: pre-normalize W into bf16 workspace (kills the 8x-redundant fp32->bf16
//     VALU work in the gemm loop), bijective XCD swizzle so the 8 M-sibling
//     blocks sharing a W tile land on ONE XCD's L2, non-temporal epilogue
//     stores (avoid RFO on 64B partial-line segments).
// R2: resubmit of R1 — previous round hit GPUAcquisitionTimeout, never ran.

#define MDIM 1024
#define KDIM 512
#define NCLS 100000

#define BM 128
#define BN 128
#define BK 32
#define LDST 40   // LDS row stride in bf16 elems: 32 + 8 pad (80 B, 16B-aligned)

#define NTILES ((NCLS + BN - 1) / BN)   // 782
#define NWG (8 * NTILES)                // 6256, divisible by 8

typedef unsigned short u16;
typedef unsigned int u32;
typedef short s16x8 __attribute__((ext_vector_type(8)));
typedef float f32x4 __attribute__((ext_vector_type(4)));

// round-to-nearest-even fp32 -> bf16, two values packed into a u32
__device__ __forceinline__ u32 pk2(float a, float b) {
  u32 ua = __builtin_bit_cast(u32, a);
  u32 ub = __builtin_bit_cast(u32, b);
  ua += 0x7FFFu + ((ua >> 16) & 1u);
  ub += 0x7FFFu + ((ub >> 16) & 1u);
  return (ua >> 16) | (ub & 0xFFFF0000u);
}

// ---- Kernel 1: L2-normalize input rows, store bf16 row-major [1024][512] ----
__global__ __launch_bounds__(256) void norm_input_kernel(const float* __restrict__ in,
                                                         u16* __restrict__ abf) {
  const int row = blockIdx.x;
  const int tid = threadIdx.x;
  const float2 v = *reinterpret_cast<const float2*>(in + (size_t)row * KDIM + 2 * tid);
  float ss = v.x * v.x + v.y * v.y;
#pragma unroll
  for (int off = 32; off > 0; off >>= 1) ss += __shfl_down(ss, off);
  __shared__ float part[4];
  if ((tid & 63) == 0) part[tid >> 6] = ss;
  __syncthreads();
  const float tot = part[0] + part[1] + part[2] + part[3];
  const float rn = 1.0f / fmaxf(sqrtf(tot), 1e-12f);  // F.normalize: x / max(||x||, eps)
  reinterpret_cast<u32*>(abf)[row * (KDIM / 2) + tid] = pk2(v.x * rn, v.y * rn);
}

// ---- Kernel 1b: L2-normalize weight rows, store bf16 row-major [100000][512] ----
// One wave per row, 4 rows per block. 204.8 MB read + 102.4 MB write, pure streaming.
__global__ __launch_bounds__(256) void norm_weight_kernel(const float* __restrict__ W,
                                                          u16* __restrict__ wbf) {
  const int row = blockIdx.x * 4 + (threadIdx.x >> 6);
  const int lane = threadIdx.x & 63;
  const float* p = W + (size_t)row * KDIM + lane * 8;
  const float4 v0 = *reinterpret_cast<const float4*>(p);
  const float4 v1 = *reinterpret_cast<const float4*>(p + 4);
  float ss = v0.x * v0.x + v0.y * v0.y + v0.z * v0.z + v0.w * v0.w
           + v1.x * v1.x + v1.y * v1.y + v1.z * v1.z + v1.w * v1.w;
#pragma unroll
  for (int off = 32; off > 0; off >>= 1) ss += __shfl_xor(ss, off);
  const float rn = 1.0f / fmaxf(sqrtf(ss), 1e-12f);
  uint4 o;
  o.x = pk2(v0.x * rn, v0.y * rn);
  o.y = pk2(v0.z * rn, v0.w * rn);
  o.z = pk2(v1.x * rn, v1.y * rn);
  o.w = pk2(v1.z * rn, v1.w * rn);
  *reinterpret_cast<uint4*>(wbf + (size_t)row * KDIM + lane * 8) = o;
}

// ---- Kernel 2 (main): C = Anorm * Wnorm^T, both bf16, fused ArcFace epilogue ----
// 128x128 tile / block, 256 threads = 4 waves 2x2, each wave 64x64 via 4x4 of 16x16x32 MFMA.
// 1D grid with bijective XCD swizzle: XCD x (= orig%8) gets wg in [x*782,(x+1)*782);
// consecutive wg iterate M fastest -> the 8 blocks sharing a W tile run on ONE XCD.
__global__ __launch_bounds__(256) void arcface_gemm_bf16(const u16* __restrict__ Abf,
                                                         const u16* __restrict__ Wbf,
                                                         const int* __restrict__ label,
                                                         float* __restrict__ out) {
  __shared__ u16 lA[BM * LDST];
  __shared__ u16 lW[BN * LDST];
  __shared__ int lbl[BM];

  const int tid = threadIdx.x;
  const int orig = blockIdx.x;
  const int wg = (orig & 7) * NTILES + (orig >> 3);
  const int m0 = (wg & 7) * BM;
  const int n0 = (wg >> 3) * BN;

  if (tid < BM) lbl[tid] = label[m0 + tid];

  // staging: thread t handles tile row r = t>>1, 16-elem half h = t&1
  const int r = tid >> 1;
  const int half = tid & 1;
  int c = n0 + r;
  if (c >= NCLS) c = NCLS - 1;  // clamp loads on the last (partial) N-tile; stores guarded

  const u16* aptr = Abf + (size_t)(m0 + r) * KDIM + half * 16;
  const u16* wptr = Wbf + (size_t)c * KDIM + half * 16;

  // register prefetch of K-chunk 0
  uint4 a0 = *(const uint4*)(aptr);
  uint4 a1 = *(const uint4*)(aptr + 8);
  uint4 b0 = *(const uint4*)(wptr);
  uint4 b1 = *(const uint4*)(wptr + 8);

  f32x4 acc[4][4] = {};

  const int lane = tid & 63;
  const int wv = tid >> 6;
  const int wm = (wv & 1) * 64;
  const int wn = (wv >> 1) * 64;
  const int ln = lane & 15;   // MFMA: col for B/D, row for A
  const int kq = lane >> 4;   // quad: k-slice for A/B frags, row-group for C/D

  const int aw = r * LDST + half * 16;  // LDS write index (elems)

  for (int kt = 0; kt < KDIM / BK; ++kt) {
    __syncthreads();  // previous iter's frag reads done
    *(uint4*)&lA[aw] = a0;
    *(uint4*)&lA[aw + 8] = a1;
    *(uint4*)&lW[aw] = b0;
    *(uint4*)&lW[aw + 8] = b1;
    __syncthreads();

    // prefetch next K-chunk into regs (issues under the MFMA block)
    if (kt < KDIM / BK - 1) {
      const u16* ap = aptr + (kt + 1) * BK;
      a0 = *(const uint4*)(ap);
      a1 = *(const uint4*)(ap + 8);
      const u16* wp = wptr + (kt + 1) * BK;
      b0 = *(const uint4*)(wp);
      b1 = *(const uint4*)(wp + 8);
    }

    // fragment loads (ds_read_b128): lane ln -> row, kq*8 -> k-slice of the 32-wide chunk
    s16x8 af[4], wf[4];
#pragma unroll
    for (int i = 0; i < 4; ++i)
      af[i] = *(const s16x8*)&lA[(wm + 16 * i + ln) * LDST + kq * 8];
#pragma unroll
    for (int j = 0; j < 4; ++j)
      wf[j] = *(const s16x8*)&lW[(wn + 16 * j + ln) * LDST + kq * 8];
#pragma unroll
    for (int i = 0; i < 4; ++i)
#pragma unroll
      for (int j = 0; j < 4; ++j)
        acc[i][j] = __builtin_amdgcn_mfma_f32_16x16x32_bf16(af[i], wf[j], acc[i][j], 0, 0, 0);
  }

  // epilogue: C/D layout col = lane&15, row = (lane>>4)*4 + reg  [verified m89/m91]
  constexpr float S_ = 30.0f;
  constexpr float COS_M = 0.87758256189037276f;
  constexpr float SIN_M = 0.47942553860420301f;
  constexpr float TH_ = -0.87758256189037276f;       // cos(pi - 0.5)
  constexpr float FALLB = 30.0f * 0.47942553860420301f * 0.5f;  // S*sin(m)*m

#pragma unroll
  for (int i = 0; i < 4; ++i) {
    const int lrow_b = wm + 16 * i + 4 * kq;
#pragma unroll
    for (int j = 0; j < 4; ++j) {
      const int col = wn + 16 * j + ln;
      const int gcol = n0 + col;
      if (gcol < NCLS) {
#pragma unroll
        for (int rg = 0; rg < 4; ++rg) {
          const int lrow = lrow_b + rg;
          const float cosv = acc[i][j][rg];
          float o = S_ * cosv;
          if (gcol == lbl[lrow]) {
            const float s2 = fmaxf(1.0f - cosv * cosv, 0.0f);
            const float sine = sqrtf(s2);
            float phi = cosv * COS_M - sine * SIN_M;
            phi = (cosv > TH_) ? phi : (cosv - FALLB);
            o = S_ * phi;
          }
          __builtin_nontemporal_store(o, &out[(size_t)(m0 + lrow) * NCLS + gcol]);
        }
      }
    }
  }
}

// ---- Fallback kernel (ws too small for bf16 W): previous proven fused version ----
__global__ __launch_bounds__(256) void arcface_gemm(const u16* __restrict__ Abf,
                                                    const float* __restrict__ W,
                                                    const int* __restrict__ label,
                                                    float* __restrict__ out) {
  __shared__ u16 lA[BM * LDST];
  __shared__ u16 lW[BN * LDST];
  __shared__ float rnw[BN];
  __shared__ int lbl[BM];

  const int tid = threadIdx.x;
  const int m0 = blockIdx.x * BM;
  const int n0 = blockIdx.y * BN;

  if (tid < BM) lbl[tid] = label[m0 + tid];

  const int r = tid >> 1;
  const int half = tid & 1;
  int c = n0 + r;
  if (c >= NCLS) c = NCLS - 1;

  const u16* aptr = Abf + (size_t)(m0 + r) * KDIM + half * 16;
  const float* wptr = W + (size_t)c * KDIM + half * 16;

  uint4 a0 = *(const uint4*)(aptr);
  uint4 a1 = *(const uint4*)(aptr + 8);
  float4 w0 = *(const float4*)(wptr);
  float4 w1 = *(const float4*)(wptr + 4);
  float4 w2 = *(const float4*)(wptr + 8);
  float4 w3 = *(const float4*)(wptr + 12);

  f32x4 acc[4][4] = {};
  float ss = 0.0f;

  const int lane = tid & 63;
  const int wv = tid >> 6;
  const int wm = (wv & 1) * 64;
  const int wn = (wv >> 1) * 64;
  const int ln = lane & 15;
  const int kq = lane >> 4;

  const int aw = r * LDST + half * 16;

  for (int kt = 0; kt < KDIM / BK; ++kt) {
    __syncthreads();
    *(uint4*)&lA[aw] = a0;
    *(uint4*)&lA[aw + 8] = a1;
    ss += w0.x * w0.x + w0.y * w0.y + w0.z * w0.z + w0.w * w0.w;
    ss += w1.x * w1.x + w1.y * w1.y + w1.z * w1.z + w1.w * w1.w;
    ss += w2.x * w2.x + w2.y * w2.y + w2.z * w2.z + w2.w * w2.w;
    ss += w3.x * w3.x + w3.y * w3.y + w3.z * w3.z + w3.w * w3.w;
    uint4 p0, p1;
    p0.x = pk2(w0.x, w0.y); p0.y = pk2(w0.z, w0.w);
    p0.z = pk2(w1.x, w1.y); p0.w = pk2(w1.z, w1.w);
    p1.x = pk2(w2.x, w2.y); p1.y = pk2(w2.z, w2.w);
    p1.z = pk2(w3.x, w3.y); p1.w = pk2(w3.z, w3.w);
    *(uint4*)&lW[aw] = p0;
    *(uint4*)&lW[aw + 8] = p1;
    __syncthreads();

    if (kt < KDIM / BK - 1) {
      const u16* ap = aptr + (kt + 1) * BK;
      a0 = *(const uint4*)(ap);
      a1 = *(const uint4*)(ap + 8);
      const float* wp = wptr + (kt + 1) * BK;
      w0 = *(const float4*)(wp);
      w1 = *(const float4*)(wp + 4);
      w2 = *(const float4*)(wp + 8);
      w3 = *(const float4*)(wp + 12);
    }

    s16x8 af[4], wf[4];
#pragma unroll
    for (int i = 0; i < 4; ++i)
      af[i] = *(const s16x8*)&lA[(wm + 16 * i + ln) * LDST + kq * 8];
#pragma unroll
    for (int j = 0; j < 4; ++j)
      wf[j] = *(const s16x8*)&lW[(wn + 16 * j + ln) * LDST + kq * 8];
#pragma unroll
    for (int i = 0; i < 4; ++i)
#pragma unroll
      for (int j = 0; j < 4; ++j)
        acc[i][j] = __builtin_amdgcn_mfma_f32_16x16x32_bf16(af[i], wf[j], acc[i][j], 0, 0, 0);
  }

  const float sst = ss + __shfl_xor(ss, 1);
  if (half == 0) rnw[r] = 1.0f / fmaxf(sqrtf(sst), 1e-12f);
  __syncthreads();

  constexpr float S_ = 30.0f;
  constexpr float COS_M = 0.87758256189037276f;
  constexpr float SIN_M = 0.47942553860420301f;
  constexpr float TH_ = -0.87758256189037276f;
  constexpr float FALLB = 30.0f * 0.47942553860420301f * 0.5f;

#pragma unroll
  for (int i = 0; i < 4; ++i) {
    const int lrow_b = wm + 16 * i + 4 * kq;
#pragma unroll
    for (int j = 0; j < 4; ++j) {
      const int col = wn + 16 * j + ln;
      const int gcol = n0 + col;
      const float rw = rnw[col];
      if (gcol < NCLS) {
#pragma unroll
        for (int rg = 0; rg < 4; ++rg) {
          const int lrow = lrow_b + rg;
          const float cosv = acc[i][j][rg] * rw;
          float o = S_ * cosv;
          if (gcol == lbl[lrow]) {
            const float s2 = fmaxf(1.0f - cosv * cosv, 0.0f);
            const float sine = sqrtf(s2);
            float phi = cosv * COS_M - sine * SIN_M;
            phi = (cosv > TH_) ? phi : (cosv - FALLB);
            o = S_ * phi;
          }
          out[(size_t)(m0 + lrow) * NCLS + gcol] = o;
        }
      }
    }
  }
}

extern "C" void kernel_launch(void* const* d_in, const int* in_sizes, int n_in,
                              void* d_out, int out_size, void* d_ws, size_t ws_size,
                              hipStream_t stream) {
  const float* input = (const float*)d_in[0];
  const int* label = (const int*)d_in[1];
  const float* weight = (const float*)d_in[2];
  float* out = (float*)d_out;
  u16* abf = (u16*)d_ws;  // 1024*512 bf16 = 1 MB normalized input

  hipLaunchKernelGGL(norm_input_kernel, dim3(MDIM), dim3(256), 0, stream, input, abf);

  const size_t a_bytes = (size_t)MDIM * KDIM * sizeof(u16);
  const size_t w_bytes = (size_t)NCLS * KDIM * sizeof(u16);
  if (ws_size >= a_bytes + w_bytes) {
    u16* wbf = abf + (size_t)MDIM * KDIM;  // 100000*512 bf16 = 102.4 MB
    hipLaunchKernelGGL(norm_weight_kernel, dim3(NCLS / 4), dim3(256), 0, stream, weight, wbf);
    hipLaunchKernelGGL(arcface_gemm_bf16, dim3(NWG), dim3(256), 0, stream, abf, wbf, label, out);
  } else {
    dim3 grid(MDIM / BM, (NCLS + BN - 1) / BN);
    hipLaunchKernelGGL(arcface_gemm, grid, dim3(256), 0, stream, abf, weight, label, out);
  }
}